// Round 5
// baseline (783.504 us; speedup 1.0000x reference)
//
#include <hip/hip_runtime.h>

// GridSamplePScan on MI355X — R4 (resubmit): CONV folded into pass 1 (NCHW
// gather), 16x4 2-D pixel tiles for gather-line locality, flow gather on
// quad 0 only. 5 passes (step=1,2,4,8,16). Images ping-pong NHWC between
// d_in[1] and a 128 MiB ws buffer; flows ping-pong HWC in d_ws; pass 5
// writes NCHW to d_out.

constexpr int Bn = 4, Ln = 32, Cn = 16, Hn = 128, Wn = 128;
constexpr int HWp = Hn * Wn;                     // 16384
constexpr int FLOW_ELEMS = Bn * Ln * 2 * HWp;    // 4,194,304 floats
constexpr int IMG_ELEMS  = Bn * Ln * Cn * HWp;   // 33,554,432 floats
constexpr int TOTAL_PIX  = Bn * Ln * HWp;        // 2,097,152
constexpr int PX_PER_BLK = 64;                   // 256 thr = 64 px * 4 quads
constexpr int NBLK = TOTAL_PIX / PX_PER_BLK;     // 32768 (256 blocks/frame)
constexpr int NXCD = 8, CHUNK = NBLK / NXCD;     // 4096 = 16 frames/XCD

// IN_NCHW: layout of imgIn (cur + gather). OUT_NCHW: layout of imgOut.
// FLOW_NCHW: layout of flowIn. flowOut always HWC. NEED_FLOW: write flows.
template<bool IN_NCHW, bool OUT_NCHW, bool FLOW_NCHW, bool NEED_FLOW>
__global__ __launch_bounds__(256)
void pscan_pass(const float* __restrict__ flowIn,
                const float* __restrict__ imgIn,
                float* __restrict__ flowOut,
                float* __restrict__ imgOut,
                int step)
{
    const int n    = (blockIdx.x & (NXCD - 1)) * CHUNK + (blockIdx.x >> 3);
    const int t    = threadIdx.x;
    const int quad = t & 3;                 // 4-channel group
    const int pxl  = t >> 2;                // 0..63 pixel within tile
    const int frame = n >> 8;               // 256 blocks per frame
    const int fb    = n & 255;
    const int ty = fb >> 3, tx = fb & 7;    // 16x4 tile grid: 8 x-tiles, 32 y-tiles
    const int b = frame >> 5, l = frame & 31;
    const int px_y = pxl >> 4, px_x = pxl & 15;
    const int h = ty * 4 + px_y, w = tx * 16 + px_x;
    const int pix = h * Wn + w;

    const size_t fframe = (size_t)frame * (2 * HWp);
    const size_t iframe = (size_t)frame * (Cn * HWp);

    // current flow at my pixel (all lanes need it for the grid)
    float fcx, fcy;
    if (FLOW_NCHW) {
        fcx = flowIn[fframe + pix];
        fcy = flowIn[fframe + HWp + pix];
    } else {
        const float2 fc = *(const float2*)&flowIn[fframe + 2 * (size_t)pix];
        fcx = fc.x; fcy = fc.y;
    }

    // current image, my 4 channels
    float4 cur;
    if (IN_NCHW) {
        const int c0 = quad * 4;
        cur.x = imgIn[iframe + (size_t)(c0 + 0) * HWp + pix];
        cur.y = imgIn[iframe + (size_t)(c0 + 1) * HWp + pix];
        cur.z = imgIn[iframe + (size_t)(c0 + 2) * HWp + pix];
        cur.w = imgIn[iframe + (size_t)(c0 + 3) * HWp + pix];
    } else {
        cur = *(const float4*)&imgIn[iframe + (size_t)pix * Cn + quad * 4];
    }

    float4 outv = cur;
    float2 outf = make_float2(fcx, fcy);

    if (l >= step) {
        float gx = (w + 0.5f) * (2.0f / Wn) - 1.0f + fcx;
        float gy = (h + 0.5f) * (2.0f / Hn) - 1.0f + fcy;
        float tt = gx + 1.0f;
        float r  = fmodf(tt, 2.0f);
        if (r < 0.0f) r += 2.0f;
        const float gxw = r - 1.0f;

        const float x = (gxw + 1.0f) * (Wn * 0.5f) - 0.5f;
        const float y = (gy  + 1.0f) * (Hn * 0.5f) - 0.5f;
        const float x0f = floorf(x), y0f = floorf(y);
        const float wx = x - x0f,    wy = y - y0f;
        const int x0 = (int)x0f, y0 = (int)y0f;
        const int x1 = x0 + 1,   y1 = y0 + 1;

        const int xc0 = min(max(x0, 0), Wn - 1), xc1 = min(max(x1, 0), Wn - 1);
        const int yc0 = min(max(y0, 0), Hn - 1), yc1 = min(max(y1, 0), Hn - 1);
        const int o00 = yc0 * Wn + xc0, o01 = yc0 * Wn + xc1;
        const int o10 = yc1 * Wn + xc0, o11 = yc1 * Wn + xc1;

        const float w00 = (1.0f - wx) * (1.0f - wy);
        const float w01 = wx * (1.0f - wy);
        const float w10 = (1.0f - wx) * wy;
        const float w11 = wx * wy;

        // flows: border pad; only quad 0 lanes do the gather + store
        if (NEED_FLOW && quad == 0) {
            const size_t fprev = (size_t)(b * Ln + (l - step)) * (2 * HWp);
            float sx, sy;
            if (FLOW_NCHW) {
                const float* __restrict__ fp0 = flowIn + fprev;
                const float* __restrict__ fp1 = flowIn + fprev + HWp;
                sx = w00*fp0[o00] + w01*fp0[o01] + w10*fp0[o10] + w11*fp0[o11];
                sy = w00*fp1[o00] + w01*fp1[o01] + w10*fp1[o10] + w11*fp1[o11];
            } else {
                const float* __restrict__ fp = flowIn + fprev;
                const float2 t00 = *(const float2*)&fp[2*o00];
                const float2 t01 = *(const float2*)&fp[2*o01];
                const float2 t10 = *(const float2*)&fp[2*o10];
                const float2 t11 = *(const float2*)&fp[2*o11];
                sx = w00*t00.x + w01*t01.x + w10*t10.x + w11*t11.x;
                sy = w00*t00.y + w01*t01.y + w10*t10.y + w11*t11.y;
            }
            outf = make_float2(fcx + sx, fcy + sy);
        }

        // images: zeros pad, masks folded into weights
        const bool vx0 = (x0 >= 0) & (x0 < Wn);
        const bool vx1 = (x1 >= 0) & (x1 < Wn);
        const bool vy0 = (y0 >= 0) & (y0 < Hn);
        const bool vy1 = (y1 >= 0) & (y1 < Hn);
        const float m00 = (vy0 & vx0) ? w00 : 0.0f;
        const float m01 = (vy0 & vx1) ? w01 : 0.0f;
        const float m10 = (vy1 & vx0) ? w10 : 0.0f;
        const float m11 = (vy1 & vx1) ? w11 : 0.0f;

        const size_t iprev = (size_t)(b * Ln + (l - step)) * (Cn * HWp);
        const float* __restrict__ ip = imgIn + iprev;
        if (IN_NCHW) {
            const int c0 = quad * 4;
            float v[4];
            #pragma unroll
            for (int j = 0; j < 4; ++j) {
                const size_t co = (size_t)(c0 + j) * HWp;
                v[j] = m00*ip[co+o00] + m01*ip[co+o01] + m10*ip[co+o10] + m11*ip[co+o11];
            }
            outv = make_float4(cur.x + v[0], cur.y + v[1], cur.z + v[2], cur.w + v[3]);
        } else {
            const float4 t00 = *(const float4*)&ip[(size_t)o00 * Cn + quad*4];
            const float4 t01 = *(const float4*)&ip[(size_t)o01 * Cn + quad*4];
            const float4 t10 = *(const float4*)&ip[(size_t)o10 * Cn + quad*4];
            const float4 t11 = *(const float4*)&ip[(size_t)o11 * Cn + quad*4];
            outv.x = cur.x + (m00*t00.x + m01*t01.x + m10*t10.x + m11*t11.x);
            outv.y = cur.y + (m00*t00.y + m01*t01.y + m10*t10.y + m11*t11.y);
            outv.z = cur.z + (m00*t00.z + m01*t01.z + m10*t10.z + m11*t11.z);
            outv.w = cur.w + (m00*t00.w + m01*t01.w + m10*t10.w + m11*t11.w);
        }
    }

    // stores
    if (NEED_FLOW && quad == 0)
        *(float2*)&flowOut[fframe + 2 * (size_t)pix] = outf;   // HWC
    if (OUT_NCHW) {
        const int c0 = quad * 4;
        imgOut[iframe + (size_t)(c0 + 0) * HWp + pix] = outv.x;
        imgOut[iframe + (size_t)(c0 + 1) * HWp + pix] = outv.y;
        imgOut[iframe + (size_t)(c0 + 2) * HWp + pix] = outv.z;
        imgOut[iframe + (size_t)(c0 + 3) * HWp + pix] = outv.w;
    } else {
        *(float4*)&imgOut[iframe + (size_t)pix * Cn + quad * 4] = outv;
    }
}

extern "C" void kernel_launch(void* const* d_in, const int* in_sizes, int n_in,
                              void* d_out, int out_size, void* d_ws, size_t ws_size,
                              hipStream_t stream) {
    const float* f_in = (const float*)d_in[0];   // flows  [4,32,2,128,128] NCHW
    float* i_io       = (float*)d_in[1];         // images NCHW (restored each call)
    float* i_out      = (float*)d_out;

    float* fA = (float*)d_ws;                    // 16 MiB HWC flows
    float* fB = fA + FLOW_ELEMS;                 // 16 MiB
    float* iW = fB + FLOW_ELEMS;                 // 128 MiB NHWC images

    const size_t need = (size_t)(2 * FLOW_ELEMS + IMG_ELEMS) * sizeof(float);

    #define P1   pscan_pass<true , false, true , true >   // NCHW in -> NHWC out (step 1)
    #define MID  pscan_pass<false, false, false, true >   // NHWC -> NHWC
    #define LAST pscan_pass<false, true , false, false>   // NHWC -> NCHW, no flow

    if (ws_size >= need) {
        P1  <<<NBLK, 256, 0, stream>>>(f_in, i_io, fA, iW,    1);
        MID <<<NBLK, 256, 0, stream>>>(fA,   iW,   fB, i_io,  2);
        MID <<<NBLK, 256, 0, stream>>>(fB,   i_io, fA, iW,    4);
        MID <<<NBLK, 256, 0, stream>>>(fA,   iW,   fB, i_io,  8);
        LAST<<<NBLK, 256, 0, stream>>>(fB,   i_io, nullptr, i_out, 16);
    } else {
        // fallback without the 128 MiB NHWC ws buffer
        P1  <<<NBLK, 256, 0, stream>>>(f_in, i_io,  fA, i_out, 1);
        MID <<<NBLK, 256, 0, stream>>>(fA,   i_out, fB, i_io,  2);
        MID <<<NBLK, 256, 0, stream>>>(fB,   i_io,  fA, i_out, 4);
        MID <<<NBLK, 256, 0, stream>>>(fA,   i_out, fB, i_io,  8);
        LAST<<<NBLK, 256, 0, stream>>>(fB,   i_io,  nullptr, i_out, 16);
    }
    #undef P1
    #undef MID
    #undef LAST
}